// Round 14
// baseline (98.912 us; speedup 1.0000x reference)
//
#include <hip/hip_runtime.h>

// SinkhornAttention — round 14: single-shot GEMM epilogues (48 KB shared LDS
// pool; MODE0 stages the whole 128x128 bf16 tile in ONE pass = 1 barrier
// instead of 8; MODE1 two 64-row passes). All values bit-identical to r13.
// Math simplification (round 0, verified): sorted_key/value reduce to the
// block-sum of K/V; Wsort/bsort are dead.

constexpr int BB   = 4;
constexpr int LL   = 4096;
constexpr int DD   = 512;
constexpr int HH   = 8;
constexpr int HDIM = 64;
constexpr int BS   = 64;
constexpr int NBLK = 64;
constexpr int MTOT = BB * LL;   // 16384

using f32x4  = __attribute__((ext_vector_type(4))) float;
typedef __attribute__((ext_vector_type(8))) __bf16 bf16x8;

static __device__ __forceinline__ ushort f2bf(float f) {
  uint u = __float_as_uint(f);
  uint r = (u + 0x7fffu + ((u >> 16) & 1u)) >> 16;   // RNE
  return (ushort)r;
}
static __device__ __forceinline__ float bf2f(ushort u) { return __uint_as_float((uint)u << 16); }
static __device__ __forceinline__ float bflo(uint u) { return __uint_as_float(u << 16); }
static __device__ __forceinline__ float bfhi(uint u) { return __uint_as_float(u & 0xffff0000u); }

// attention-tile swizzle (64x64 bf16 tile, row stride 128 B)
static __device__ __forceinline__ int swb(int row, int cb) {
  return (row << 6) + ((cb ^ ((row & 7) << 4)) >> 1);
}

#define GLOBAL_AS(p) ((const __attribute__((address_space(1))) void*)(p))
#define LDS_AS(p)    ((__attribute__((address_space(3))) void*)(p))
#define SB0()        __builtin_amdgcn_sched_barrier(0)

// ------- fused prep: blocks [0,8192) cast x -> bf16; [8192,9216) transpose ---
__global__ __launch_bounds__(256) void prep_fused(
    const float* __restrict__ x_in, ushort* __restrict__ xb,
    const float* __restrict__ Wq, const float* __restrict__ Wk,
    const float* __restrict__ Wv, const float* __restrict__ Wo,
    ushort* __restrict__ Wqkv_t, ushort* __restrict__ Wout_t)
{
  __shared__ float tile[32][33];
  const int bid = blockIdx.x;
  if (bid < 8192) {
    const int i = bid * 256 + threadIdx.x;
    float4 v = reinterpret_cast<const float4*>(x_in)[i];
    ushort4 o;
    o.x = f2bf(v.x); o.y = f2bf(v.y); o.z = f2bf(v.z); o.w = f2bf(v.w);
    reinterpret_cast<ushort4*>(xb)[i] = o;
  } else {
    const int rem = bid - 8192;               // 0..1023
    const int z  = rem >> 8;                  // 0..3
    const float* src = (z == 0) ? Wq : (z == 1) ? Wk : (z == 2) ? Wv : Wo;
    ushort* dst = (z < 3) ? (Wqkv_t + (size_t)z * 512 * 512) : Wout_t;
    const int tx = threadIdx.x & 31, ty = threadIdx.x >> 5;   // 32 x 8
    const int r0 = ((rem >> 4) & 15) * 32, c0 = (rem & 15) * 32;
    #pragma unroll
    for (int q = 0; q < 4; ++q)
      tile[ty + 8 * q][tx] = src[(size_t)(r0 + ty + 8 * q) * 512 + c0 + tx];
    __syncthreads();
    #pragma unroll
    for (int q = 0; q < 4; ++q)
      dst[(size_t)(c0 + ty + 8 * q) * 512 + r0 + tx] = f2bf(tile[tx][ty + 8 * q]);
  }
}

// ---------------- pipelined MFMA GEMM: C[M,N] = A[M,512] @ Bt[N,512]^T + b ---
// Block tile 128x128, BK=32, 4 waves (2x2), 3-deep LDS pipeline (48 KB ->
// 3 blocks/CU), counted vmcnt(4) gates, 1 raw barrier per K-step,
// (row>>1)&3 granule swizzle (2-way = free ds_read_b128).
// Single-shot epilogue from the shared 48 KB pool.
// MODE 0: bf16 into Q/K/V (tile-uniform tensor+bias select). MODE 1: f32 out.
template<int MODE>
__global__ __launch_bounds__(256, 3) void gemm_pipe3(
    const ushort* __restrict__ A, const ushort* __restrict__ Bt,
    const float* __restrict__ b0, const float* __restrict__ b1,
    const float* __restrict__ b2,
    ushort* __restrict__ Cq, ushort* __restrict__ Ck, ushort* __restrict__ Cv,
    float* __restrict__ Cf, int N, int NBX)
{
  constexpr int K  = 512;
  constexpr int NT = K / 32;          // 16 K-steps
  constexpr int TN = 128;
  __shared__ __align__(16) ushort smem[3 * 128 * 32 * 2];   // 48 KB pool
  ushort* sAp = smem;                                        // 3 x 8 KB
  ushort* sBp = smem + 3 * 128 * 32;                         // 3 x 8 KB

  const int tid  = threadIdx.x;
  const int lane = tid & 63;
  const int w    = tid >> 6;
  const int wr   = w >> 1, wc = w & 1;
  const int lr   = lane & 15;
  const int kq   = lane >> 4;

  // XCD-chunked block swizzle (grid % 8 == 0), nb fastest within a chunk
  const int nwg  = NBX * 128;
  const int cpx  = nwg >> 3;
  const int swz  = ((int)blockIdx.x & 7) * cpx + ((int)blockIdx.x >> 3);
  const int nb   = swz % NBX;
  const int mb   = swz / NBX;
  const int brow = mb * 128;
  const int bcol = nb * TN;

  auto stageA = [&](int buf, int t, int j) {
    const int c   = j * 256 + tid;
    const int row = c >> 2, ch = c & 3;
    const ushort* src = A + (size_t)(brow + row) * K + t * 32 + ((ch ^ ((row >> 1) & 3)) << 3);
    __builtin_amdgcn_global_load_lds(GLOBAL_AS(src),
        LDS_AS(&sAp[buf * 4096 + ((j * 256 + (w << 6)) << 3)]), 16, 0, 0);
  };
  auto stageB = [&](int buf, int t, int j) {
    const int c   = j * 256 + tid;
    const int row = c >> 2, ch = c & 3;
    const ushort* src = Bt + (size_t)(bcol + row) * K + t * 32 + ((ch ^ ((row >> 1) & 3)) << 3);
    __builtin_amdgcn_global_load_lds(GLOBAL_AS(src),
        LDS_AS(&sBp[buf * 4096 + ((j * 256 + (w << 6)) << 3)]), 16, 0, 0);
  };
  auto ldA = [&](int buf, int mf) -> bf16x8 {
    const int row = (wr << 6) + (mf << 4) + lr;
    return *reinterpret_cast<const bf16x8*>(
        &sAp[buf * 4096 + (row << 5) + ((kq ^ ((row >> 1) & 3)) << 3)]);
  };
  auto ldB = [&](int buf, int nf) -> bf16x8 {
    const int row = (wc << 6) + (nf << 4) + lr;
    return *reinterpret_cast<const bf16x8*>(
        &sBp[buf * 4096 + (row << 5) + ((kq ^ ((row >> 1) & 3)) << 3)]);
  };

  f32x4 acc[4][4];
  #pragma unroll
  for (int mi = 0; mi < 4; ++mi)
    #pragma unroll
    for (int ni = 0; ni < 4; ++ni)
      acc[mi][ni] = (f32x4){0.f, 0.f, 0.f, 0.f};

  // ---- prologue: stage K-steps 0 and 1
  stageA(0, 0, 0); stageA(0, 0, 1); stageB(0, 0, 0); stageB(0, 0, 1);
  stageA(1, 1, 0); stageA(1, 1, 1); stageB(1, 1, 0); stageB(1, 1, 1);
  asm volatile("s_waitcnt vmcnt(4)" ::: "memory");
  SB0(); __builtin_amdgcn_s_barrier(); SB0();

  for (int t = 0; t < NT; ++t) {
    const int buf  = t % 3;
    const int nbuf = (t + 2) % 3;
    const bool more = (t + 2) < NT;

    bf16x8 af[4], bfr[4];
    #pragma unroll
    for (int mf = 0; mf < 4; ++mf) af[mf] = ldA(buf, mf);
    #pragma unroll
    for (int nf = 0; nf < 4; ++nf) bfr[nf] = ldB(buf, nf);
    if (more) { stageA(nbuf, t + 2, 0); stageA(nbuf, t + 2, 1);
                stageB(nbuf, t + 2, 0); stageB(nbuf, t + 2, 1); }
    SB0();
    __builtin_amdgcn_s_setprio(1);
    #pragma unroll
    for (int mi = 0; mi < 4; ++mi)
      #pragma unroll
      for (int ni = 0; ni < 4; ++ni)
        acc[mi][ni] = __builtin_amdgcn_mfma_f32_16x16x32_bf16(af[mi], bfr[ni], acc[mi][ni], 0, 0, 0);
    __builtin_amdgcn_s_setprio(0);
    SB0();
    if (more) asm volatile("s_waitcnt vmcnt(4)" ::: "memory");
    else      asm volatile("s_waitcnt vmcnt(0)" ::: "memory");
    SB0(); __builtin_amdgcn_s_barrier(); SB0();
  }

  // ---- epilogue: single-shot LDS staging from 48 KB pool (bit-identical) ----
  if constexpr (MODE == 0) {
    // whole 128 x 128 bf16 tile: 128 x (128+8) = 34.8 KB, ONE barrier.
    ushort* sEp = smem;
    constexpr int ES = TN + 8;
    const int which = bcol >> 9;                  // tile-uniform tensor select
    ushort* dst = (which == 0) ? Cq : ((which == 1) ? Ck : Cv);
    const float* bsel = (which == 0) ? b0 : ((which == 1) ? b1 : b2);
    const int ncol0 = bcol & 511;
    #pragma unroll
    for (int mi = 0; mi < 4; ++mi) {
      #pragma unroll
      for (int nf = 0; nf < 4; ++nf) {
        const int col = wc * 64 + nf * 16 + lr;
        const float bb = bsel[ncol0 + col];
        const int row0 = wr * 64 + mi * 16 + kq * 4;
        #pragma unroll
        for (int r = 0; r < 4; ++r)
          sEp[(row0 + r) * ES + col] = f2bf(acc[mi][nf][r] + bb);
      }
    }
    __syncthreads();
    #pragma unroll
    for (int it = 0; it < 8; ++it) {
      const int idx = tid + it * 256;             // 2048 16-B chunks
      const int rr  = idx >> 4;                   // 0..127
      const int cc  = (idx & 15) * 8;
      uint4 v = *reinterpret_cast<const uint4*>(&sEp[rr * ES + cc]);
      *reinterpret_cast<uint4*>(&dst[(size_t)(brow + rr) * DD + ncol0 + cc]) = v;
    }
  } else {
    // f32: two 64-row passes of 64 x (128+8) = 34 KB each.
    float* sEpF = (float*)smem;
    constexpr int ES = TN + 8;
    #pragma unroll
    for (int half = 0; half < 2; ++half) {        // half == wr-group
      if (half) __syncthreads();
      if (wr == half) {
        #pragma unroll
        for (int mi = 0; mi < 4; ++mi) {
          #pragma unroll
          for (int nf = 0; nf < 4; ++nf) {
            const int col = wc * 64 + nf * 16 + lr;
            const float bb = b0[bcol + col];
            const int row0 = mi * 16 + kq * 4;
            #pragma unroll
            for (int r = 0; r < 4; ++r)
              sEpF[(row0 + r) * ES + col] = acc[mi][nf][r] + bb;
          }
        }
      }
      __syncthreads();
      #pragma unroll
      for (int it = 0; it < 8; ++it) {
        const int idx = tid + it * 256;           // 2048 16-B chunks
        const int rr  = idx >> 5;                 // 0..63
        const int cc  = (idx & 31) * 4;
        float4 v = *reinterpret_cast<const float4*>(&sEpF[rr * ES + cc]);
        *reinterpret_cast<float4*>(&Cf[(size_t)(brow + half * 64 + rr) * N + bcol + cc]) = v;
      }
    }
  }
}

// ---------------- fused block-sum of K,V -> Khi/Klo/Vb (no atomics) ----------
__global__ __launch_bounds__(256) void sumkv_fused(
    const ushort* __restrict__ K, const ushort* __restrict__ V,
    ushort* __restrict__ Khi, ushort* __restrict__ Klo, ushort* __restrict__ Vb)
{
  __shared__ float kbuf[4][64][9];
  __shared__ float vbuf[4][64][9];
  const int bs   = blockIdx.x;          // b*64 + s
  const int b    = bs >> 6, s = bs & 63;
  const int lane = threadIdx.x & 63;
  const int kbq  = threadIdx.x >> 6;
  const size_t rowbase = ((size_t)b * LL + s) * DD + lane * 8;

  uint4 ku[16], vu[16];
  #pragma unroll
  for (int i = 0; i < 16; ++i) {
    const size_t off = rowbase + (size_t)(kbq * 16 + i) * BS * DD;
    ku[i] = *reinterpret_cast<const uint4*>(K + off);
    vu[i] = *reinterpret_cast<const uint4*>(V + off);
  }
  float ak[8] = {0,0,0,0,0,0,0,0}, av[8] = {0,0,0,0,0,0,0,0};
  #pragma unroll
  for (int i = 0; i < 16; ++i) {
    ak[0] += bflo(ku[i].x); ak[1] += bfhi(ku[i].x); ak[2] += bflo(ku[i].y); ak[3] += bfhi(ku[i].y);
    ak[4] += bflo(ku[i].z); ak[5] += bfhi(ku[i].z); ak[6] += bflo(ku[i].w); ak[7] += bfhi(ku[i].w);
    av[0] += bflo(vu[i].x); av[1] += bfhi(vu[i].x); av[2] += bflo(vu[i].y); av[3] += bfhi(vu[i].y);
    av[4] += bflo(vu[i].z); av[5] += bfhi(vu[i].z); av[6] += bflo(vu[i].w); av[7] += bfhi(vu[i].w);
  }
  #pragma unroll
  for (int j = 0; j < 8; ++j) { kbuf[kbq][lane][j] = ak[j]; vbuf[kbq][lane][j] = av[j]; }
  __syncthreads();

  const size_t wbase = (size_t)bs * DD + lane * 8;
  if (kbq == 0) {
    uint4 hi4, lo4;
    uint* hp = reinterpret_cast<uint*>(&hi4);
    uint* lp = reinterpret_cast<uint*>(&lo4);
    #pragma unroll
    for (int p = 0; p < 4; ++p) {
      uint hw = 0, lw = 0;
      #pragma unroll
      for (int q = 0; q < 2; ++q) {
        const int j = p * 2 + q;
        const float t = kbuf[0][lane][j] + kbuf[1][lane][j] +
                        kbuf[2][lane][j] + kbuf[3][lane][j];
        const ushort h = f2bf(t);
        const ushort l = f2bf(t - bf2f(h));
        hw |= (uint)h << (16 * q);
        lw |= (uint)l << (16 * q);
      }
      hp[p] = hw; lp[p] = lw;
    }
    *reinterpret_cast<uint4*>(Khi + wbase) = hi4;
    *reinterpret_cast<uint4*>(Klo + wbase) = lo4;
  } else if (kbq == 1) {
    uint4 o4;
    uint* op = reinterpret_cast<uint*>(&o4);
    #pragma unroll
    for (int p = 0; p < 4; ++p) {
      uint wv = 0;
      #pragma unroll
      for (int q = 0; q < 2; ++q) {
        const int j = p * 2 + q;
        const float t = vbuf[0][lane][j] + vbuf[1][lane][j] +
                        vbuf[2][lane][j] + vbuf[3][lane][j];
        wv |= (uint)f2bf(t) << (16 * q);
      }
      op[p] = wv;
    }
    *reinterpret_cast<uint4*>(Vb + wbase) = o4;
  }
}

// ---------------- MFMA two-pass block attention ------------------------------
// 24 KB LDS (sP aliased onto Klo buffer sCP) -> 6 blocks/CU; XCD-chunked grid.
__global__ __launch_bounds__(256) void attn_mfma(
    const ushort* __restrict__ Q, const ushort* __restrict__ Kg,
    const ushort* __restrict__ Vg, const ushort* __restrict__ Khi,
    const ushort* __restrict__ Klo, const ushort* __restrict__ Vsb,
    ushort* __restrict__ X)
{
  __shared__ __align__(16) ushort sA[64 * 64];   // K (pass1), Khi (pass2)
  __shared__ __align__(16) ushort sVt[64 * 64];  // V^T, then Vsum^T
  __shared__ __align__(16) ushort sCP[64 * 64];  // P (both passes) / Klo (pass2)
  const int bid = blockIdx.x;
  const int swz = (bid & 7) * 256 + (bid >> 3);  // XCD-chunked (2048 % 8 == 0)
  const int n = swz & 63, h = (swz >> 6) & 7, b = swz >> 9;
  const int tid  = threadIdx.x;
  const int lane = tid & 63;
  const int w    = tid >> 6;
  const int lr   = lane & 15, hi4 = lane >> 4;
  const float scale = 0.125f;

  const size_t tbase = ((size_t)(b * LL + n * BS)) * DD + h * HDIM;
  const size_t sbase = ((size_t)(b * BS)) * DD + h * HDIM;

  uint4 k1[2], v1[2], k2h[2], k2l[2], v2[2];
  int rr[2], cc[2];
  #pragma unroll
  for (int it = 0; it < 2; ++it) {
    const int i  = tid + it * 256;      // 0..511
    const int r  = i >> 3;
    const int c8 = (i & 7) << 3;
    rr[it] = r; cc[it] = c8;
    const size_t g1 = tbase + (size_t)r * DD + c8;
    const size_t g2 = sbase + (size_t)r * DD + c8;
    k1[it]  = *reinterpret_cast<const uint4*>(Kg  + g1);
    v1[it]  = *reinterpret_cast<const uint4*>(Vg  + g1);
    k2h[it] = *reinterpret_cast<const uint4*>(Khi + g2);
    k2l[it] = *reinterpret_cast<const uint4*>(Klo + g2);
    v2[it]  = *reinterpret_cast<const uint4*>(Vsb + g2);
  }
  bf16x8 qf[2];
  #pragma unroll
  for (int ks = 0; ks < 2; ++ks)
    qf[ks] = *reinterpret_cast<const bf16x8*>(
        Q + tbase + (size_t)(w * 16 + lr) * DD + ks * 32 + hi4 * 8);

  #pragma unroll
  for (int it = 0; it < 2; ++it) {
    *reinterpret_cast<uint4*>(&sA[swb(rr[it], cc[it] << 1)]) = k1[it];
    const uint u[4] = {v1[it].x, v1[it].y, v1[it].z, v1[it].w};
    #pragma unroll
    for (int j = 0; j < 4; ++j) {
      sVt[swb(cc[it] + 2 * j,     rr[it] << 1)] = (ushort)(u[j] & 0xffff);
      sVt[swb(cc[it] + 2 * j + 1, rr[it] << 1)] = (ushort)(u[j] >> 16);
    }
  }
  __syncthreads();

  f32x4 xacc[4];
  #pragma unroll
  for (int dt = 0; dt < 4; ++dt) xacc[dt] = (f32x4){0.f, 0.f, 0.f, 0.f};

  // ================= PASS 1 =================
  {
    f32x4 st[4];
    #pragma unroll
    for (int t = 0; t < 4; ++t) st[t] = (f32x4){0.f, 0.f, 0.f, 0.f};
    #pragma unroll
    for (int ks = 0; ks < 2; ++ks) {
      #pragma unroll
      for (int t = 0; t < 4; ++t) {
        bf16x8 kf = *reinterpret_cast<const bf16x8*>(
            &sA[swb(t * 16 + lr, (ks * 32 + hi4 * 8) << 1)]);
        st[t] = __builtin_amdgcn_mfma_f32_16x16x32_bf16(kf, qf[ks], st[t], 0, 0, 0);
      }
    }
    float e[4][4];
    float mx = -1e30f;
    #pragma unroll
    for (int t = 0; t < 4; ++t)
      #pragma unroll
      for (int r = 0; r < 4; ++r) { e[t][r] = st[t][r] * scale; mx = fmaxf(mx, e[t][r]); }
    mx = fmaxf(mx, __shfl_xor(mx, 16));
    mx = fmaxf(mx, __shfl_xor(mx, 32));
    float sum = 0.f;
    #pragma unroll
    for (int t = 0; t < 4; ++t)
      #pragma unroll
      for (int r = 0; r < 4; ++r) { e[t][r] = __expf(e[t][r] - mx); sum += e[t][r]; }
    sum += __shfl_xor(sum, 16);
    sum += __shfl_xor(sum, 32);
    const float inv = 1.0f / sum;
    #pragma unroll
    for (int t = 0; t < 4; ++t) {
      ushort4 p4;
      p4.x = f2bf(e[t][0] * inv); p4.y = f2bf(e[t][1] * inv);
      p4.z = f2bf(e[t][2] * inv); p4.w = f2bf(e[t][3] * inv);
      *reinterpret_cast<ushort4*>(&sCP[swb(w * 16 + lr, (t * 16 + hi4 * 4) << 1)]) = p4;
    }
    #pragma unroll
    for (int ks = 0; ks < 2; ++ks) {
      bf16x8 pa = *reinterpret_cast<const bf16x8*>(
          &sCP[swb(w * 16 + lr, (ks * 32 + hi4 * 8) << 1)]);
      #pragma unroll
      for (int dt = 0; dt < 4; ++dt) {
        bf16x8 vb = *reinterpret_cast<const bf16x8*>(
            &sVt[swb(dt * 16 + lr, (ks * 32 + hi4 * 8) << 1)]);
        xacc[dt] = __builtin_amdgcn_mfma_f32_16x16x32_bf16(pa, vb, xacc[dt], 0, 0, 0);
      }
    }
  }
  __syncthreads();

  #pragma unroll
  for (int it = 0; it < 2; ++it) {
    *reinterpret_cast<uint4*>(&sA[swb(rr[it], cc[it] << 1)])  = k2h[it];
    *reinterpret_cast<uint4*>(&sCP[swb(rr[it], cc[it] << 1)]) = k2l[it];
    const uint u[4] = {v2[it].x, v2[it].y, v2[it].z, v2[it].w};
    #pragma unroll
    for (int j = 0; j < 4; ++j) {
      sVt[swb(cc[it] + 2 * j,     rr[it] << 1)] = (ushort)(u[j] & 0xffff);
      sVt[swb(cc[it] + 2 * j + 1, rr[it] << 1)] = (ushort)(u[j] >> 16);
    }
  }
  __syncthreads();

  // ================= PASS 2 =================
  {
    f32x4 st[4];
    #pragma unroll
    for (int t = 0; t < 4; ++t) st[t] = (f32x4){0.f, 0.f, 0.f, 0.f};
    #pragma unroll
    for (int ks = 0; ks < 2; ++ks) {
      #pragma unroll
      for (int t = 0; t < 4; ++t) {
        bf16x8 kh = *reinterpret_cast<const bf16x8*>(
            &sA[swb(t * 16 + lr, (ks * 32 + hi4 * 8) << 1)]);
        st[t] = __builtin_amdgcn_mfma_f32_16x16x32_bf16(kh, qf[ks], st[t], 0, 0, 0);
        bf16x8 kl = *reinterpret_cast<const bf16x8*>(
            &sCP[swb(t * 16 + lr, (ks * 32 + hi4 * 8) << 1)]);
        st[t] = __builtin_amdgcn_mfma_f32_16x16x32_bf16(kl, qf[ks], st[t], 0, 0, 0);
      }
    }
    __syncthreads();   // all Klo reads done before P overwrites sCP
    float e[4][4];
    float mx = -1e30f;
    #pragma unroll
    for (int t = 0; t < 4; ++t)
      #pragma unroll
      for (int r = 0; r < 4; ++r) { e[t][r] = st[t][r] * scale; mx = fmaxf(mx, e[t][r]); }
    mx = fmaxf(mx, __shfl_xor(mx, 16));
    mx = fmaxf(mx, __shfl_xor(mx, 32));
    float sum = 0.f;
    #pragma unroll
    for (int t = 0; t < 4; ++t)
      #pragma unroll
      for (int r = 0; r < 4; ++r) { e[t][r] = __expf(e[t][r] - mx); sum += e[t][r]; }
    sum += __shfl_xor(sum, 16);
    sum += __shfl_xor(sum, 32);
    const float inv = 1.0f / sum;
    #pragma unroll
    for (int t = 0; t < 4; ++t) {
      ushort4 p4;
      p4.x = f2bf(e[t][0] * inv); p4.y = f2bf(e[t][1] * inv);
      p4.z = f2bf(e[t][2] * inv); p4.w = f2bf(e[t][3] * inv);
      *reinterpret_cast<ushort4*>(&sCP[swb(w * 16 + lr, (t * 16 + hi4 * 4) << 1)]) = p4;
    }
    #pragma unroll
    for (int ks = 0; ks < 2; ++ks) {
      bf16x8 pa = *reinterpret_cast<const bf16x8*>(
          &sCP[swb(w * 16 + lr, (ks * 32 + hi4 * 8) << 1)]);
      #pragma unroll
      for (int dt = 0; dt < 4; ++dt) {
        bf16x8 vb = *reinterpret_cast<const bf16x8*>(
            &sVt[swb(dt * 16 + lr, (ks * 32 + hi4 * 8) << 1)]);
        xacc[dt] = __builtin_amdgcn_mfma_f32_16x16x32_bf16(pa, vb, xacc[dt], 0, 0, 0);
      }
    }
  }

  #pragma unroll
  for (int dt = 0; dt < 4; ++dt)
    #pragma unroll
    for (int r = 0; r < 4; ++r)
      X[tbase + (size_t)(w * 16 + hi4 * 4 + r) * DD + dt * 16 + lr] = f2bf(xacc[dt][r]);
}

// ---------------- launcher ---------------------------------------------------
extern "C" void kernel_launch(void* const* d_in, const int* in_sizes, int n_in,
                              void* d_out, int out_size, void* d_ws, size_t ws_size,
                              hipStream_t stream) {
  const float* x_in = (const float*)d_in[0];
  const float* Wq   = (const float*)d_in[1];
  const float* bq   = (const float*)d_in[2];
  const float* Wk   = (const float*)d_in[3];
  const float* bk   = (const float*)d_in[4];
  const float* Wv   = (const float*)d_in[5];
  const float* bv   = (const float*)d_in[6];
  const float* Wout = (const float*)d_in[9];
  const float* bout = (const float*)d_in[10];
  float* out = (float*)d_out;

  const size_t NTOK = (size_t)MTOT * DD;          // 8,388,608 elems
  const size_t NSUM = (size_t)BB * BS * DD;       // 131072 elems
  char* ws = (char*)d_ws;
  ushort* xb      = (ushort*)ws;            ws += NTOK * 2;
  ushort* Qb      = (ushort*)ws;            ws += NTOK * 2;
  ushort* Kb      = (ushort*)ws;            ws += NTOK * 2;
  ushort* Vb      = (ushort*)ws;            ws += NTOK * 2;
  ushort* Xb      = (ushort*)ws;            ws += NTOK * 2;
  ushort* Wqkv_t  = (ushort*)ws;            ws += (size_t)1536 * 512 * 2;
  ushort* Wout_t  = (ushort*)ws;            ws += (size_t)512 * 512 * 2;
  ushort* KhiB    = (ushort*)ws;            ws += NSUM * 2;
  ushort* KloB    = (ushort*)ws;            ws += NSUM * 2;
  ushort* VsB     = (ushort*)ws;            ws += NSUM * 2;

  // fused prep: 8192 cast blocks + 1024 transpose blocks
  prep_fused<<<8192 + 1024, 256, 0, stream>>>(
      x_in, xb, Wq, Wk, Wv, Wout, Wqkv_t, Wout_t);

  // QKV: tile 128x128, grid 12*128 = 1536 (3 blocks/CU -> exactly 2 rounds)
  gemm_pipe3<0><<<12 * 128, 256, 0, stream>>>(
      xb, Wqkv_t, bq, bk, bv, Qb, Kb, Vb, nullptr, 1536, 12);

  sumkv_fused<<<BB * BS, 256, 0, stream>>>(Kb, Vb, KhiB, KloB, VsB);

  attn_mfma<<<BB * HH * NBLK, 256, 0, stream>>>(Qb, Kb, Vb, KhiB, KloB, VsB, Xb);

  // out: tile 128x128, grid 4*128 = 512 (fully resident at 3 blocks/CU)
  gemm_pipe3<1><<<4 * 128, 256, 0, stream>>>(
      Xb, Wout_t, bout, nullptr, nullptr, nullptr, nullptr, nullptr, out, 512, 4);
}

// Round 15
// 98.055 us; speedup vs baseline: 1.0087x; 1.0087x over previous
//
#include <hip/hip_runtime.h>

// SinkhornAttention — round 15: sumkv column-split (grid 256x2, uint2 loads,
// 2 blocks/CU) to lift its effective HBM BW. Everything else = r13/r14 best.
// All math bit-identical (absmax margin 0.75 / 0.76).
// Math simplification (round 0, verified): sorted_key/value reduce to the
// block-sum of K/V; Wsort/bsort are dead.

constexpr int BB   = 4;
constexpr int LL   = 4096;
constexpr int DD   = 512;
constexpr int HH   = 8;
constexpr int HDIM = 64;
constexpr int BS   = 64;
constexpr int NBLK = 64;
constexpr int MTOT = BB * LL;   // 16384

using f32x4  = __attribute__((ext_vector_type(4))) float;
typedef __attribute__((ext_vector_type(8))) __bf16 bf16x8;

static __device__ __forceinline__ ushort f2bf(float f) {
  uint u = __float_as_uint(f);
  uint r = (u + 0x7fffu + ((u >> 16) & 1u)) >> 16;   // RNE
  return (ushort)r;
}
static __device__ __forceinline__ float bf2f(ushort u) { return __uint_as_float((uint)u << 16); }
static __device__ __forceinline__ float bflo(uint u) { return __uint_as_float(u << 16); }
static __device__ __forceinline__ float bfhi(uint u) { return __uint_as_float(u & 0xffff0000u); }

// attention-tile swizzle (64x64 bf16 tile, row stride 128 B)
static __device__ __forceinline__ int swb(int row, int cb) {
  return (row << 6) + ((cb ^ ((row & 7) << 4)) >> 1);
}

#define GLOBAL_AS(p) ((const __attribute__((address_space(1))) void*)(p))
#define LDS_AS(p)    ((__attribute__((address_space(3))) void*)(p))
#define SB0()        __builtin_amdgcn_sched_barrier(0)

// ------- fused prep: blocks [0,8192) cast x -> bf16; [8192,9216) transpose ---
__global__ __launch_bounds__(256) void prep_fused(
    const float* __restrict__ x_in, ushort* __restrict__ xb,
    const float* __restrict__ Wq, const float* __restrict__ Wk,
    const float* __restrict__ Wv, const float* __restrict__ Wo,
    ushort* __restrict__ Wqkv_t, ushort* __restrict__ Wout_t)
{
  __shared__ float tile[32][33];
  const int bid = blockIdx.x;
  if (bid < 8192) {
    const int i = bid * 256 + threadIdx.x;
    float4 v = reinterpret_cast<const float4*>(x_in)[i];
    ushort4 o;
    o.x = f2bf(v.x); o.y = f2bf(v.y); o.z = f2bf(v.z); o.w = f2bf(v.w);
    reinterpret_cast<ushort4*>(xb)[i] = o;
  } else {
    const int rem = bid - 8192;               // 0..1023
    const int z  = rem >> 8;                  // 0..3
    const float* src = (z == 0) ? Wq : (z == 1) ? Wk : (z == 2) ? Wv : Wo;
    ushort* dst = (z < 3) ? (Wqkv_t + (size_t)z * 512 * 512) : Wout_t;
    const int tx = threadIdx.x & 31, ty = threadIdx.x >> 5;   // 32 x 8
    const int r0 = ((rem >> 4) & 15) * 32, c0 = (rem & 15) * 32;
    #pragma unroll
    for (int q = 0; q < 4; ++q)
      tile[ty + 8 * q][tx] = src[(size_t)(r0 + ty + 8 * q) * 512 + c0 + tx];
    __syncthreads();
    #pragma unroll
    for (int q = 0; q < 4; ++q)
      dst[(size_t)(c0 + ty + 8 * q) * 512 + r0 + tx] = f2bf(tile[tx][ty + 8 * q]);
  }
}

// ---------------- pipelined MFMA GEMM: C[M,N] = A[M,512] @ Bt[N,512]^T + b ---
// Block tile 128x128, BK=32, 4 waves (2x2), 3-deep LDS pipeline (48 KB ->
// 3 blocks/CU), counted vmcnt(4) gates, 1 raw barrier per K-step,
// (row>>1)&3 granule swizzle (2-way = free ds_read_b128).
// MODE 0: bf16 into Q/K/V (tile-uniform tensor+bias select). MODE 1: f32 out.
template<int MODE>
__global__ __launch_bounds__(256, 3) void gemm_pipe3(
    const ushort* __restrict__ A, const ushort* __restrict__ Bt,
    const float* __restrict__ b0, const float* __restrict__ b1,
    const float* __restrict__ b2,
    ushort* __restrict__ Cq, ushort* __restrict__ Ck, ushort* __restrict__ Cv,
    float* __restrict__ Cf, int N, int NBX)
{
  constexpr int K  = 512;
  constexpr int NT = K / 32;          // 16 K-steps
  constexpr int TN = 128;
  __shared__ __align__(16) ushort smem[3 * 128 * 32 * 2];   // 48 KB pool
  ushort* sAp = smem;                                        // 3 x 8 KB
  ushort* sBp = smem + 3 * 128 * 32;                         // 3 x 8 KB

  const int tid  = threadIdx.x;
  const int lane = tid & 63;
  const int w    = tid >> 6;
  const int wr   = w >> 1, wc = w & 1;
  const int lr   = lane & 15;
  const int kq   = lane >> 4;

  // XCD-chunked block swizzle (grid % 8 == 0), nb fastest within a chunk
  const int nwg  = NBX * 128;
  const int cpx  = nwg >> 3;
  const int swz  = ((int)blockIdx.x & 7) * cpx + ((int)blockIdx.x >> 3);
  const int nb   = swz % NBX;
  const int mb   = swz / NBX;
  const int brow = mb * 128;
  const int bcol = nb * TN;

  auto stageA = [&](int buf, int t, int j) {
    const int c   = j * 256 + tid;
    const int row = c >> 2, ch = c & 3;
    const ushort* src = A + (size_t)(brow + row) * K + t * 32 + ((ch ^ ((row >> 1) & 3)) << 3);
    __builtin_amdgcn_global_load_lds(GLOBAL_AS(src),
        LDS_AS(&sAp[buf * 4096 + ((j * 256 + (w << 6)) << 3)]), 16, 0, 0);
  };
  auto stageB = [&](int buf, int t, int j) {
    const int c   = j * 256 + tid;
    const int row = c >> 2, ch = c & 3;
    const ushort* src = Bt + (size_t)(bcol + row) * K + t * 32 + ((ch ^ ((row >> 1) & 3)) << 3);
    __builtin_amdgcn_global_load_lds(GLOBAL_AS(src),
        LDS_AS(&sBp[buf * 4096 + ((j * 256 + (w << 6)) << 3)]), 16, 0, 0);
  };
  auto ldA = [&](int buf, int mf) -> bf16x8 {
    const int row = (wr << 6) + (mf << 4) + lr;
    return *reinterpret_cast<const bf16x8*>(
        &sAp[buf * 4096 + (row << 5) + ((kq ^ ((row >> 1) & 3)) << 3)]);
  };
  auto ldB = [&](int buf, int nf) -> bf16x8 {
    const int row = (wc << 6) + (nf << 4) + lr;
    return *reinterpret_cast<const bf16x8*>(
        &sBp[buf * 4096 + (row << 5) + ((kq ^ ((row >> 1) & 3)) << 3)]);
  };

  f32x4 acc[4][4];
  #pragma unroll
  for (int mi = 0; mi < 4; ++mi)
    #pragma unroll
    for (int ni = 0; ni < 4; ++ni)
      acc[mi][ni] = (f32x4){0.f, 0.f, 0.f, 0.f};

  // ---- prologue: stage K-steps 0 and 1
  stageA(0, 0, 0); stageA(0, 0, 1); stageB(0, 0, 0); stageB(0, 0, 1);
  stageA(1, 1, 0); stageA(1, 1, 1); stageB(1, 1, 0); stageB(1, 1, 1);
  asm volatile("s_waitcnt vmcnt(4)" ::: "memory");
  SB0(); __builtin_amdgcn_s_barrier(); SB0();

  for (int t = 0; t < NT; ++t) {
    const int buf  = t % 3;
    const int nbuf = (t + 2) % 3;
    const bool more = (t + 2) < NT;

    bf16x8 af[4], bfr[4];
    #pragma unroll
    for (int mf = 0; mf < 4; ++mf) af[mf] = ldA(buf, mf);
    #pragma unroll
    for (int nf = 0; nf < 4; ++nf) bfr[nf] = ldB(buf, nf);
    if (more) { stageA(nbuf, t + 2, 0); stageA(nbuf, t + 2, 1);
                stageB(nbuf, t + 2, 0); stageB(nbuf, t + 2, 1); }
    SB0();
    __builtin_amdgcn_s_setprio(1);
    #pragma unroll
    for (int mi = 0; mi < 4; ++mi)
      #pragma unroll
      for (int ni = 0; ni < 4; ++ni)
        acc[mi][ni] = __builtin_amdgcn_mfma_f32_16x16x32_bf16(af[mi], bfr[ni], acc[mi][ni], 0, 0, 0);
    __builtin_amdgcn_s_setprio(0);
    SB0();
    if (more) asm volatile("s_waitcnt vmcnt(4)" ::: "memory");
    else      asm volatile("s_waitcnt vmcnt(0)" ::: "memory");
    SB0(); __builtin_amdgcn_s_barrier(); SB0();
  }

  // ---- epilogue: single-shot LDS staging from 48 KB pool (bit-identical) ----
  if constexpr (MODE == 0) {
    ushort* sEp = smem;
    constexpr int ES = TN + 8;
    const int which = bcol >> 9;
    ushort* dst = (which == 0) ? Cq : ((which == 1) ? Ck : Cv);
    const float* bsel = (which == 0) ? b0 : ((which == 1) ? b1 : b2);
    const int ncol0 = bcol & 511;
    #pragma unroll
    for (int mi = 0; mi < 4; ++mi) {
      #pragma unroll
      for (int nf = 0; nf < 4; ++nf) {
        const int col = wc * 64 + nf * 16 + lr;
        const float bb = bsel[ncol0 + col];
        const int row0 = wr * 64 + mi * 16 + kq * 4;
        #pragma unroll
        for (int r = 0; r < 4; ++r)
          sEp[(row0 + r) * ES + col] = f2bf(acc[mi][nf][r] + bb);
      }
    }
    __syncthreads();
    #pragma unroll
    for (int it = 0; it < 8; ++it) {
      const int idx = tid + it * 256;             // 2048 16-B chunks
      const int rr  = idx >> 4;                   // 0..127
      const int cc  = (idx & 15) * 8;
      uint4 v = *reinterpret_cast<const uint4*>(&sEp[rr * ES + cc]);
      *reinterpret_cast<uint4*>(&dst[(size_t)(brow + rr) * DD + ncol0 + cc]) = v;
    }
  } else {
    float* sEpF = (float*)smem;
    constexpr int ES = TN + 8;
    #pragma unroll
    for (int half = 0; half < 2; ++half) {
      if (half) __syncthreads();
      if (wr == half) {
        #pragma unroll
        for (int mi = 0; mi < 4; ++mi) {
          #pragma unroll
          for (int nf = 0; nf < 4; ++nf) {
            const int col = wc * 64 + nf * 16 + lr;
            const float bb = b0[bcol + col];
            const int row0 = mi * 16 + kq * 4;
            #pragma unroll
            for (int r = 0; r < 4; ++r)
              sEpF[(row0 + r) * ES + col] = acc[mi][nf][r] + bb;
          }
        }
      }
      __syncthreads();
      #pragma unroll
      for (int it = 0; it < 8; ++it) {
        const int idx = tid + it * 256;
        const int rr  = idx >> 5;
        const int cc  = (idx & 31) * 4;
        float4 v = *reinterpret_cast<const float4*>(&sEpF[rr * ES + cc]);
        *reinterpret_cast<float4*>(&Cf[(size_t)(brow + half * 64 + rr) * N + bcol + cc]) = v;
      }
    }
  }
}

// ---------------- fused block-sum of K,V -> Khi/Klo/Vb (no atomics) ----------
// Grid (256, 2): blockIdx.x = (b,s), blockIdx.y = column half (256 ch each).
// Per-thread uint2 (4 cols) x 16 kb; summation order per output element
// identical to prior rounds (kb ascending per wave, 4-wave LDS tree).
__global__ __launch_bounds__(256) void sumkv_fused(
    const ushort* __restrict__ K, const ushort* __restrict__ V,
    ushort* __restrict__ Khi, ushort* __restrict__ Klo, ushort* __restrict__ Vb)
{
  __shared__ float kbuf[4][64][5];
  __shared__ float vbuf[4][64][5];
  const int bs   = blockIdx.x;          // b*64 + s
  const int b    = bs >> 6, s = bs & 63;
  const int ch0  = blockIdx.y * 256;    // column-half base
  const int lane = threadIdx.x & 63;
  const int kbq  = threadIdx.x >> 6;
  const size_t rowbase = ((size_t)b * LL + s) * DD + ch0 + lane * 4;

  uint2 ku[16], vu[16];
  #pragma unroll
  for (int i = 0; i < 16; ++i) {
    const size_t off = rowbase + (size_t)(kbq * 16 + i) * BS * DD;
    ku[i] = *reinterpret_cast<const uint2*>(K + off);
    vu[i] = *reinterpret_cast<const uint2*>(V + off);
  }
  float ak[4] = {0,0,0,0}, av[4] = {0,0,0,0};
  #pragma unroll
  for (int i = 0; i < 16; ++i) {
    ak[0] += bflo(ku[i].x); ak[1] += bfhi(ku[i].x);
    ak[2] += bflo(ku[i].y); ak[3] += bfhi(ku[i].y);
    av[0] += bflo(vu[i].x); av[1] += bfhi(vu[i].x);
    av[2] += bflo(vu[i].y); av[3] += bfhi(vu[i].y);
  }
  #pragma unroll
  for (int j = 0; j < 4; ++j) { kbuf[kbq][lane][j] = ak[j]; vbuf[kbq][lane][j] = av[j]; }
  __syncthreads();

  const size_t wbase = (size_t)bs * DD + ch0 + lane * 4;
  if (kbq == 0) {
    uint2 hi2, lo2;
    uint* hp = reinterpret_cast<uint*>(&hi2);
    uint* lp = reinterpret_cast<uint*>(&lo2);
    #pragma unroll
    for (int p = 0; p < 2; ++p) {
      uint hw = 0, lw = 0;
      #pragma unroll
      for (int q = 0; q < 2; ++q) {
        const int j = p * 2 + q;
        const float t = kbuf[0][lane][j] + kbuf[1][lane][j] +
                        kbuf[2][lane][j] + kbuf[3][lane][j];
        const ushort h = f2bf(t);
        const ushort l = f2bf(t - bf2f(h));
        hw |= (uint)h << (16 * q);
        lw |= (uint)l << (16 * q);
      }
      hp[p] = hw; lp[p] = lw;
    }
    *reinterpret_cast<uint2*>(Khi + wbase) = hi2;
    *reinterpret_cast<uint2*>(Klo + wbase) = lo2;
  } else if (kbq == 1) {
    uint2 o2;
    uint* op = reinterpret_cast<uint*>(&o2);
    #pragma unroll
    for (int p = 0; p < 2; ++p) {
      uint wv = 0;
      #pragma unroll
      for (int q = 0; q < 2; ++q) {
        const int j = p * 2 + q;
        const float t = vbuf[0][lane][j] + vbuf[1][lane][j] +
                        vbuf[2][lane][j] + vbuf[3][lane][j];
        wv |= (uint)f2bf(t) << (16 * q);
      }
      op[p] = wv;
    }
    *reinterpret_cast<uint2*>(Vb + wbase) = o2;
  }
}

// ---------------- MFMA two-pass block attention ------------------------------
// 24 KB LDS (sP aliased onto Klo buffer sCP) -> 6 blocks/CU; XCD-chunked grid.
__global__ __launch_bounds__(256) void attn_mfma(
    const ushort* __restrict__ Q, const ushort* __restrict__ Kg,
    const ushort* __restrict__ Vg, const ushort* __restrict__ Khi,
    const ushort* __restrict__ Klo, const ushort* __restrict__ Vsb,
    ushort* __restrict__ X)
{
  __shared__ __align__(16) ushort sA[64 * 64];   // K (pass1), Khi (pass2)
  __shared__ __align__(16) ushort sVt[64 * 64];  // V^T, then Vsum^T
  __shared__ __align__(16) ushort sCP[64 * 64];  // P (both passes) / Klo (pass2)
  const int bid = blockIdx.x;
  const int swz = (bid & 7) * 256 + (bid >> 3);  // XCD-chunked (2048 % 8 == 0)
  const int n = swz & 63, h = (swz >> 6) & 7, b = swz >> 9;
  const int tid  = threadIdx.x;
  const int lane = tid & 63;
  const int w    = tid >> 6;
  const int lr   = lane & 15, hi4 = lane >> 4;
  const float scale = 0.125f;

  const size_t tbase = ((size_t)(b * LL + n * BS)) * DD + h * HDIM;
  const size_t sbase = ((size_t)(b * BS)) * DD + h * HDIM;

  uint4 k1[2], v1[2], k2h[2], k2l[2], v2[2];
  int rr[2], cc[2];
  #pragma unroll
  for (int it = 0; it < 2; ++it) {
    const int i  = tid + it * 256;      // 0..511
    const int r  = i >> 3;
    const int c8 = (i & 7) << 3;
    rr[it] = r; cc[it] = c8;
    const size_t g1 = tbase + (size_t)r * DD + c8;
    const size_t g2 = sbase + (size_t)r * DD + c8;
    k1[it]  = *reinterpret_cast<const uint4*>(Kg  + g1);
    v1[it]  = *reinterpret_cast<const uint4*>(Vg  + g1);
    k2h[it] = *reinterpret_cast<const uint4*>(Khi + g2);
    k2l[it] = *reinterpret_cast<const uint4*>(Klo + g2);
    v2[it]  = *reinterpret_cast<const uint4*>(Vsb + g2);
  }
  bf16x8 qf[2];
  #pragma unroll
  for (int ks = 0; ks < 2; ++ks)
    qf[ks] = *reinterpret_cast<const bf16x8*>(
        Q + tbase + (size_t)(w * 16 + lr) * DD + ks * 32 + hi4 * 8);

  #pragma unroll
  for (int it = 0; it < 2; ++it) {
    *reinterpret_cast<uint4*>(&sA[swb(rr[it], cc[it] << 1)]) = k1[it];
    const uint u[4] = {v1[it].x, v1[it].y, v1[it].z, v1[it].w};
    #pragma unroll
    for (int j = 0; j < 4; ++j) {
      sVt[swb(cc[it] + 2 * j,     rr[it] << 1)] = (ushort)(u[j] & 0xffff);
      sVt[swb(cc[it] + 2 * j + 1, rr[it] << 1)] = (ushort)(u[j] >> 16);
    }
  }
  __syncthreads();

  f32x4 xacc[4];
  #pragma unroll
  for (int dt = 0; dt < 4; ++dt) xacc[dt] = (f32x4){0.f, 0.f, 0.f, 0.f};

  // ================= PASS 1 =================
  {
    f32x4 st[4];
    #pragma unroll
    for (int t = 0; t < 4; ++t) st[t] = (f32x4){0.f, 0.f, 0.f, 0.f};
    #pragma unroll
    for (int ks = 0; ks < 2; ++ks) {
      #pragma unroll
      for (int t = 0; t < 4; ++t) {
        bf16x8 kf = *reinterpret_cast<const bf16x8*>(
            &sA[swb(t * 16 + lr, (ks * 32 + hi4 * 8) << 1)]);
        st[t] = __builtin_amdgcn_mfma_f32_16x16x32_bf16(kf, qf[ks], st[t], 0, 0, 0);
      }
    }
    float e[4][4];
    float mx = -1e30f;
    #pragma unroll
    for (int t = 0; t < 4; ++t)
      #pragma unroll
      for (int r = 0; r < 4; ++r) { e[t][r] = st[t][r] * scale; mx = fmaxf(mx, e[t][r]); }
    mx = fmaxf(mx, __shfl_xor(mx, 16));
    mx = fmaxf(mx, __shfl_xor(mx, 32));
    float sum = 0.f;
    #pragma unroll
    for (int t = 0; t < 4; ++t)
      #pragma unroll
      for (int r = 0; r < 4; ++r) { e[t][r] = __expf(e[t][r] - mx); sum += e[t][r]; }
    sum += __shfl_xor(sum, 16);
    sum += __shfl_xor(sum, 32);
    const float inv = 1.0f / sum;
    #pragma unroll
    for (int t = 0; t < 4; ++t) {
      ushort4 p4;
      p4.x = f2bf(e[t][0] * inv); p4.y = f2bf(e[t][1] * inv);
      p4.z = f2bf(e[t][2] * inv); p4.w = f2bf(e[t][3] * inv);
      *reinterpret_cast<ushort4*>(&sCP[swb(w * 16 + lr, (t * 16 + hi4 * 4) << 1)]) = p4;
    }
    #pragma unroll
    for (int ks = 0; ks < 2; ++ks) {
      bf16x8 pa = *reinterpret_cast<const bf16x8*>(
          &sCP[swb(w * 16 + lr, (ks * 32 + hi4 * 8) << 1)]);
      #pragma unroll
      for (int dt = 0; dt < 4; ++dt) {
        bf16x8 vb = *reinterpret_cast<const bf16x8*>(
            &sVt[swb(dt * 16 + lr, (ks * 32 + hi4 * 8) << 1)]);
        xacc[dt] = __builtin_amdgcn_mfma_f32_16x16x32_bf16(pa, vb, xacc[dt], 0, 0, 0);
      }
    }
  }
  __syncthreads();

  #pragma unroll
  for (int it = 0; it < 2; ++it) {
    *reinterpret_cast<uint4*>(&sA[swb(rr[it], cc[it] << 1)])  = k2h[it];
    *reinterpret_cast<uint4*>(&sCP[swb(rr[it], cc[it] << 1)]) = k2l[it];
    const uint u[4] = {v2[it].x, v2[it].y, v2[it].z, v2[it].w};
    #pragma unroll
    for (int j = 0; j < 4; ++j) {
      sVt[swb(cc[it] + 2 * j,     rr[it] << 1)] = (ushort)(u[j] & 0xffff);
      sVt[swb(cc[it] + 2 * j + 1, rr[it] << 1)] = (ushort)(u[j] >> 16);
    }
  }
  __syncthreads();

  // ================= PASS 2 =================
  {
    f32x4 st[4];
    #pragma unroll
    for (int t = 0; t < 4; ++t) st[t] = (f32x4){0.f, 0.f, 0.f, 0.f};
    #pragma unroll
    for (int ks = 0; ks < 2; ++ks) {
      #pragma unroll
      for (int t = 0; t < 4; ++t) {
        bf16x8 kh = *reinterpret_cast<const bf16x8*>(
            &sA[swb(t * 16 + lr, (ks * 32 + hi4 * 8) << 1)]);
        st[t] = __builtin_amdgcn_mfma_f32_16x16x32_bf16(kh, qf[ks], st[t], 0, 0, 0);
        bf16x8 kl = *reinterpret_cast<const bf16x8*>(
            &sCP[swb(t * 16 + lr, (ks * 32 + hi4 * 8) << 1)]);
        st[t] = __builtin_amdgcn_mfma_f32_16x16x32_bf16(kl, qf[ks], st[t], 0, 0, 0);
      }
    }
    __syncthreads();   // all Klo reads done before P overwrites sCP
    float e[4][4];
    float mx = -1e30f;
    #pragma unroll
    for (int t = 0; t < 4; ++t)
      #pragma unroll
      for (int r = 0; r < 4; ++r) { e[t][r] = st[t][r] * scale; mx = fmaxf(mx, e[t][r]); }
    mx = fmaxf(mx, __shfl_xor(mx, 16));
    mx = fmaxf(mx, __shfl_xor(mx, 32));
    float sum = 0.f;
    #pragma unroll
    for (int t = 0; t < 4; ++t)
      #pragma unroll
      for (int r = 0; r < 4; ++r) { e[t][r] = __expf(e[t][r] - mx); sum += e[t][r]; }
    sum += __shfl_xor(sum, 16);
    sum += __shfl_xor(sum, 32);
    const float inv = 1.0f / sum;
    #pragma unroll
    for (int t = 0; t < 4; ++t) {
      ushort4 p4;
      p4.x = f2bf(e[t][0] * inv); p4.y = f2bf(e[t][1] * inv);
      p4.z = f2bf(e[t][2] * inv); p4.w = f2bf(e[t][3] * inv);
      *reinterpret_cast<ushort4*>(&sCP[swb(w * 16 + lr, (t * 16 + hi4 * 4) << 1)]) = p4;
    }
    #pragma unroll
    for (int ks = 0; ks < 2; ++ks) {
      bf16x8 pa = *reinterpret_cast<const bf16x8*>(
          &sCP[swb(w * 16 + lr, (ks * 32 + hi4 * 8) << 1)]);
      #pragma unroll
      for (int dt = 0; dt < 4; ++dt) {
        bf16x8 vb = *reinterpret_cast<const bf16x8*>(
            &sVt[swb(dt * 16 + lr, (ks * 32 + hi4 * 8) << 1)]);
        xacc[dt] = __builtin_amdgcn_mfma_f32_16x16x32_bf16(pa, vb, xacc[dt], 0, 0, 0);
      }
    }
  }

  #pragma unroll
  for (int dt = 0; dt < 4; ++dt)
    #pragma unroll
    for (int r = 0; r < 4; ++r)
      X[tbase + (size_t)(w * 16 + hi4 * 4 + r) * DD + dt * 16 + lr] = f2bf(xacc[dt][r]);
}

// ---------------- launcher ---------------------------------------------------
extern "C" void kernel_launch(void* const* d_in, const int* in_sizes, int n_in,
                              void* d_out, int out_size, void* d_ws, size_t ws_size,
                              hipStream_t stream) {
  const float* x_in = (const float*)d_in[0];
  const float* Wq   = (const float*)d_in[1];
  const float* bq   = (const float*)d_in[2];
  const float* Wk   = (const float*)d_in[3];
  const float* bk   = (const float*)d_in[4];
  const float* Wv   = (const float*)d_in[5];
  const float* bv   = (const float*)d_in[6];
  const float* Wout = (const float*)d_in[9];
  const float* bout = (const float*)d_in[10];
  float* out = (float*)d_out;

  const size_t NTOK = (size_t)MTOT * DD;          // 8,388,608 elems
  const size_t NSUM = (size_t)BB * BS * DD;       // 131072 elems
  char* ws = (char*)d_ws;
  ushort* xb      = (ushort*)ws;            ws += NTOK * 2;
  ushort* Qb      = (ushort*)ws;            ws += NTOK * 2;
  ushort* Kb      = (ushort*)ws;            ws += NTOK * 2;
  ushort* Vb      = (ushort*)ws;            ws += NTOK * 2;
  ushort* Xb      = (ushort*)ws;            ws += NTOK * 2;
  ushort* Wqkv_t  = (ushort*)ws;            ws += (size_t)1536 * 512 * 2;
  ushort* Wout_t  = (ushort*)ws;            ws += (size_t)512 * 512 * 2;
  ushort* KhiB    = (ushort*)ws;            ws += NSUM * 2;
  ushort* KloB    = (ushort*)ws;            ws += NSUM * 2;
  ushort* VsB     = (ushort*)ws;            ws += NSUM * 2;

  // fused prep: 8192 cast blocks + 1024 transpose blocks
  prep_fused<<<8192 + 1024, 256, 0, stream>>>(
      x_in, xb, Wq, Wk, Wv, Wout, Wqkv_t, Wout_t);

  // QKV: tile 128x128, grid 12*128 = 1536 (3 blocks/CU -> exactly 2 rounds)
  gemm_pipe3<0><<<12 * 128, 256, 0, stream>>>(
      xb, Wqkv_t, bq, bk, bv, Qb, Kb, Vb, nullptr, 1536, 12);

  // sumkv: grid (256 x 2) — column-split for 2 blocks/CU
  sumkv_fused<<<dim3(BB * BS, 2), 256, 0, stream>>>(Kb, Vb, KhiB, KloB, VsB);

  attn_mfma<<<BB * HH * NBLK, 256, 0, stream>>>(Qb, Kb, Vb, KhiB, KloB, VsB, Xb);

  // out: tile 128x128, grid 4*128 = 512 (fully resident at 3 blocks/CU)
  gemm_pipe3<1><<<4 * 128, 256, 0, stream>>>(
      Xb, Wout_t, bout, nullptr, nullptr, nullptr, nullptr, nullptr, out, 512, 4);
}